// Round 3
// baseline (473.874 us; speedup 1.0000x reference)
//
#include <hip/hip_runtime.h>

typedef __attribute__((ext_vector_type(8))) __bf16 bf16x8;
typedef __attribute__((ext_vector_type(4)))  float f32x4;
typedef __attribute__((ext_vector_type(16))) float f32x16;

__device__ __forceinline__ unsigned short f2bfu(float x) {
  union { float f; unsigned u; } v; v.f = x;
  unsigned r = v.u + 0x7fffu + ((v.u >> 16) & 1u);
  return (unsigned short)(r >> 16);
}
__device__ __forceinline__ float bf2f(unsigned short u) {
  union { unsigned u; float f; } v; v.u = ((unsigned)u) << 16;
  return v.f;
}
__device__ __forceinline__ unsigned pkbf(float a, float b) {
  return (unsigned)f2bfu(a) | ((unsigned)f2bfu(b) << 16);
}
__device__ __forceinline__ void gload16(const void* g, void* l) {
  __builtin_amdgcn_global_load_lds((const __attribute__((address_space(1))) unsigned*)g,
                                   (__attribute__((address_space(3))) unsigned*)l, 16, 0, 0);
}
__device__ __forceinline__ bf16x8 mk8(unsigned a, unsigned b, unsigned c, unsigned d) {
  union { unsigned u[4]; bf16x8 v; } t;
  t.u[0] = a; t.u[1] = b; t.u[2] = c; t.u[3] = d; return t.v;
}

// ---------- fp32 -> bf16 convert ----------
__global__ void cvt_kernel(const float* __restrict__ s, short* __restrict__ d, int n) {
  int i = (blockIdx.x * 256 + threadIdx.x) * 4;
  if (i >= n) return;
  float4 v = *(const float4*)(s + i);
  short4 o;
  o.x = (short)f2bfu(v.x); o.y = (short)f2bfu(v.y);
  o.z = (short)f2bfu(v.z); o.w = (short)f2bfu(v.w);
  *(short4*)(d + i) = o;
}

// ---------- fp32 [R][C] -> bf16 [C][R] (weight transpose+convert) ----------
__global__ void transcvt_kernel(const float* __restrict__ src, short* __restrict__ dst,
                                int R, int C) {
  __shared__ __align__(16) float tl[64][65];
  int c0 = blockIdx.x * 64, r0 = blockIdx.y * 64;
  int t = threadIdx.x;
  int tr = t >> 4, tc = (t & 15) * 4;
#pragma unroll
  for (int i = 0; i < 4; i++) {
    int r = i * 16 + tr;
    float4 v = *(const float4*)(src + (size_t)(r0 + r) * C + c0 + tc);
    tl[r][tc] = v.x; tl[r][tc + 1] = v.y; tl[r][tc + 2] = v.z; tl[r][tc + 3] = v.w;
  }
  __syncthreads();
#pragma unroll
  for (int i = 0; i < 4; i++) {
    int cr = i * 16 + tr;
    short4 o;
    o.x = (short)f2bfu(tl[tc][cr]);
    o.y = (short)f2bfu(tl[tc + 1][cr]);
    o.z = (short)f2bfu(tl[tc + 2][cr]);
    o.w = (short)f2bfu(tl[tc + 3][cr]);
    *(short4*)(dst + (size_t)(c0 + cr) * R + r0 + tc) = o;
  }
}

// ---------- cos/sin table ----------
__global__ void sincos_kernel(const float* __restrict__ freqs, float* __restrict__ ct,
                              float* __restrict__ st) {
  int i = blockIdx.x * 256 + threadIdx.x; // 65536 = 2048*32
  float f = freqs[i];
  ct[i] = cosf(f);
  st[i] = sinf(f);
}

// ---------- bf16 GEMM: A[M][K] @ Bt[N][K]^T -> C[M][N]; m97 structure ----------
template <int OUTF32>
__global__ __launch_bounds__(256) void gemm_bt(const short* __restrict__ A,
                                               const short* __restrict__ Bt,
                                               void* __restrict__ C, int M, int N, int K) {
  __shared__ __align__(16) short Al[128 * 32];
  __shared__ __align__(16) short Bl[128 * 32];
  const int t = threadIdx.x, lane = t & 63, w = t >> 6;
  const int m0 = blockIdx.x * 128, n0 = blockIdx.y * 128;
  const int wm = (w & 1) * 64, wn = (w >> 1) * 64;
  f32x4 acc[4][4];
#pragma unroll
  for (int i = 0; i < 4; i++)
#pragma unroll
    for (int j = 0; j < 4; j++)
#pragma unroll
      for (int r = 0; r < 4; r++) acc[i][j][r] = 0.f;

  const int sr = t >> 2;  // staging row 0..63 (+64 on pass 1)
  const int ss = t & 3;   // 16B slot
  const int ldsbase = w * 512;  // elements

  for (int k0 = 0; k0 < K; k0 += 32) {
    __syncthreads();
#pragma unroll
    for (int p = 0; p < 2; p++) {
      int r = p * 64 + sr;
      int c = 8 * (ss ^ ((r >> 1) & 3));  // source-side swizzle, LDS stays linear
      gload16(A + (size_t)(m0 + r) * K + k0 + c, &Al[p * 2048 + ldsbase]);
      gload16(Bt + (size_t)(n0 + r) * K + k0 + c, &Bl[p * 2048 + ldsbase]);
    }
    __syncthreads();
    bf16x8 af[4], bg[4];
#pragma unroll
    for (int i = 0; i < 4; i++) {
      int ra = wm + i * 16 + (lane & 15);
      int sa = (lane >> 4) ^ ((ra >> 1) & 3);
      af[i] = *(const bf16x8*)(&Al[ra * 32 + sa * 8]);
      int rb = wn + i * 16 + (lane & 15);
      int sb = (lane >> 4) ^ ((rb >> 1) & 3);
      bg[i] = *(const bf16x8*)(&Bl[rb * 32 + sb * 8]);
    }
#pragma unroll
    for (int i = 0; i < 4; i++)
#pragma unroll
      for (int j = 0; j < 4; j++)
        acc[i][j] = __builtin_amdgcn_mfma_f32_16x16x32_bf16(af[i], bg[j], acc[i][j], 0, 0, 0);
  }
  const int cr = (lane >> 4) * 4, cc = lane & 15;
#pragma unroll
  for (int i = 0; i < 4; i++)
#pragma unroll
    for (int j = 0; j < 4; j++)
#pragma unroll
      for (int r = 0; r < 4; r++) {
        size_t idx = (size_t)(m0 + wm + i * 16 + cr + r) * N + (n0 + wn + j * 16 + cc);
        if (OUTF32) ((float*)C)[idx] = acc[i][j][r];
        else        ((short*)C)[idx] = (short)f2bfu(acc[i][j][r]);
      }
}

// ---------- RoPE in-place on qkv (Q cols 0..2047, K cols 2048..2559) ----------
__global__ void rope_kernel(short* __restrict__ qkv, const float* __restrict__ ct,
                            const float* __restrict__ st) {
  int idx = blockIdx.x * 256 + threadIdx.x;
  const int PQ = 4096 * 1024;
  int row, col, i;
  if (idx < PQ) {
    row = idx >> 10; int p = idx & 1023; int h = p >> 5; i = p & 31;
    col = h * 64 + 2 * i;
  } else {
    int k = idx - PQ; row = k >> 8; int p = k & 255; int kvh = p >> 5; i = p & 31;
    col = 2048 + kvh * 64 + 2 * i;
  }
  int s = row & 2047;
  unsigned* ptr = (unsigned*)(qkv + (size_t)row * 3072 + col);
  unsigned v = *ptr;
  float tr = bf2f((unsigned short)(v & 0xffff));
  float ti = bf2f((unsigned short)(v >> 16));
  float c = ct[(s << 5) + i], sn = st[(s << 5) + i];
  *ptr = pkbf(tr * c - ti * sn, tr * sn + ti * c);
}

// ---------- V transpose: qkv cols [2560..3071] -> vt[(b*8+kv)*64+d][s] ----------
__global__ void transv_kernel(const short* __restrict__ qkv, short* __restrict__ vt) {
  __shared__ __align__(16) short tl[64][72];
  int st0 = blockIdx.x * 64;
  int bkv = blockIdx.y; int b = bkv >> 3, kv = bkv & 7;
  int t = threadIdx.x;
  int rr = t >> 3, c8 = (t & 7) * 8;
#pragma unroll
  for (int i = 0; i < 2; i++) {
    int sl = i * 32 + rr;
    bf16x8 v = *(const bf16x8*)(qkv + (size_t)(b * 2048 + st0 + sl) * 3072 + 2560 + kv * 64 + c8);
    union { bf16x8 v; short s[8]; } u; u.v = v;
#pragma unroll
    for (int j = 0; j < 8; j++) tl[sl][c8 + j] = u.s[j];
  }
  __syncthreads();
#pragma unroll
  for (int i = 0; i < 2; i++) {
    int dl = i * 32 + rr;
    union { bf16x8 v; short s[8]; } o;
#pragma unroll
    for (int j = 0; j < 8; j++) o.s[j] = tl[c8 + j][dl];
    *(bf16x8*)(vt + ((size_t)(bkv * 64 + dl)) * 2048 + st0 + c8) = o.v;
  }
}

// ---------- causal GQA flash attention ----------
// grid (S/128, H, B); 4 waves x 32 q-rows; KVBLK=32; swapped QK^T; O^T accumulation
__global__ __launch_bounds__(256) void attn_kernel(const short* __restrict__ qkv,
                                                   const short* __restrict__ vt,
                                                   short* __restrict__ attn) {
  const int S = 2048, NC = 3072;
  __shared__ __align__(16) short kl[32 * 64];      // K tile [k 32][d 64], slot-swz ^(row&7)
  __shared__ __align__(16) short vl[64 * 32];      // V^T tile [d 64][k 32], slot-swz ^((d>>1)&3)
  __shared__ __align__(16) short ol[4][32 * 72];   // epilogue

  const int qb = blockIdx.x * 128;
  const int h = blockIdx.y, b = blockIdx.z;
  const int kvh = h >> 2;
  const int t = threadIdx.x, lane = t & 63, w = t >> 6;
  const int q0 = qb + w * 32;
  const int qc = lane & 31, hi = lane >> 5;
  const int qg = q0 + qc;

  bf16x8 bq[4];
  {
    const short* qp = qkv + (size_t)(b * S + qg) * NC + h * 64 + hi * 8;
#pragma unroll
    for (int kk = 0; kk < 4; kk++) bq[kk] = *(const bf16x8*)(qp + kk * 16);
  }

  f32x16 ot0, ot1;
#pragma unroll
  for (int r = 0; r < 16; r++) { ot0[r] = 0.f; ot1[r] = 0.f; }
  float m = -1e30f, l = 0.f;

  const int kr = w * 8 + (lane >> 3), sk = lane & 7;
  const short* kbase = qkv + (size_t)(b * S + kr) * NC + 2048 + kvh * 64 + 8 * (sk ^ (kr & 7));
  const int dv = w * 16 + (lane >> 2), sv = lane & 3;
  const short* vbase = vt + ((size_t)((b * 8 + kvh) * 64 + dv)) * S + 8 * (sv ^ ((dv >> 1) & 3));

  const int nt = (qb >> 5) + 4;
  for (int tile = 0; tile < nt; ++tile) {
    const int s0 = tile * 32;
    __syncthreads();
    gload16(kbase + (size_t)s0 * NC, &kl[w * 512]);
    gload16(vbase + s0, &vl[w * 512]);
    __syncthreads();

    // swapped QK^T: S^T[k][q]
    f32x16 cs;
#pragma unroll
    for (int r = 0; r < 16; r++) cs[r] = 0.f;
    const int krow = lane & 31;
#pragma unroll
    for (int kk = 0; kk < 4; kk++) {
      int slot = (2 * kk + hi) ^ (krow & 7);
      bf16x8 ak = *(const bf16x8*)(&kl[krow * 64 + slot * 8]);
      cs = __builtin_amdgcn_mfma_f32_32x32x16_bf16(ak, bq[kk], cs, 0, 0, 0);
    }

    float e[16];
    const bool notfull = (s0 + 31 > q0);
#pragma unroll
    for (int r = 0; r < 16; r++) {
      float sv_ = cs[r] * 0.18033688011112042f;  // 0.125 * log2(e)
      if (notfull) {
        int kgl = s0 + (r & 3) + 8 * (r >> 2) + 4 * hi;
        if (kgl > qg) sv_ = -1e30f;
      }
      e[r] = sv_;
    }
    float mx = e[0];
#pragma unroll
    for (int r = 1; r < 16; r++) mx = fmaxf(mx, e[r]);
    mx = fmaxf(mx, __shfl_xor(mx, 32, 64));
    float mn = fmaxf(m, mx);
    float rf = exp2f(m - mn);
    m = mn;
    float p[16]; float ls = 0.f;
#pragma unroll
    for (int r = 0; r < 16; r++) { p[r] = exp2f(e[r] - mn); ls += p[r]; }
    l = l * rf + ls;
#pragma unroll
    for (int r = 0; r < 16; r++) { ot0[r] *= rf; ot1[r] *= rf; }

    // P^T -> B-fragments (pack + half-swap)
    unsigned x[8], y[8];
#pragma unroll
    for (int j = 0; j < 8; j++) x[j] = pkbf(p[2 * j], p[2 * j + 1]);
#pragma unroll
    for (int j = 0; j < 8; j++) y[j] = (unsigned)__shfl_xor((int)x[j], 32, 64);
    bf16x8 pb0 = hi ? mk8(y[2], y[3], x[2], x[3]) : mk8(x[0], x[1], y[0], y[1]);
    bf16x8 pb1 = hi ? mk8(y[6], y[7], x[6], x[7]) : mk8(x[4], x[5], y[4], y[5]);

    const int dl = lane & 31;
#pragma unroll
    for (int ks = 0; ks < 2; ks++) {
      bf16x8 pb = ks ? pb1 : pb0;
#pragma unroll
      for (int dh = 0; dh < 2; dh++) {
        int d = dh * 32 + dl;
        int slot = (2 * ks + hi) ^ ((d >> 1) & 3);
        bf16x8 av = *(const bf16x8*)(&vl[d * 32 + slot * 8]);
        if (dh == 0) ot0 = __builtin_amdgcn_mfma_f32_32x32x16_bf16(av, pb, ot0, 0, 0, 0);
        else         ot1 = __builtin_amdgcn_mfma_f32_32x32x16_bf16(av, pb, ot1, 0, 0, 0);
      }
    }
  }

  float lt = l + __shfl_xor(l, 32, 64);
  float inv = 1.0f / lt;
#pragma unroll
  for (int dh = 0; dh < 2; dh++) {
#pragma unroll
    for (int j = 0; j < 8; j++) {
      int d = ((2 * j) & 3) + 8 * ((2 * j) >> 2) + 4 * hi + 32 * dh;
      float a = (dh ? ot1[2 * j] : ot0[2 * j]) * inv;
      float bb = (dh ? ot1[2 * j + 1] : ot0[2 * j + 1]) * inv;
      *(unsigned*)(&ol[w][qc * 72 + d]) = pkbf(a, bb);
    }
  }
  __syncthreads();
  const int qr = lane >> 1, part = lane & 1;
  short* og = attn + (size_t)(b * S + q0 + qr) * 2048 + h * 64 + part * 32;
  const short* ip = &ol[w][qr * 72 + part * 32];
#pragma unroll
  for (int i2 = 0; i2 < 4; i2++) *(bf16x8*)(og + i2 * 8) = *(const bf16x8*)(ip + i2 * 8);
}

extern "C" void kernel_launch(void* const* d_in, const int* in_sizes, int n_in,
                              void* d_out, int out_size, void* d_ws, size_t ws_size,
                              hipStream_t stream) {
  (void)in_sizes; (void)n_in; (void)out_size; (void)ws_size;
  const float* x     = (const float*)d_in[0];
  const float* wq    = (const float*)d_in[1];
  const float* wk    = (const float*)d_in[2];
  const float* wv    = (const float*)d_in[3];
  const float* wo    = (const float*)d_in[4];
  const float* freqs = (const float*)d_in[5];

  char* ws = (char*)d_ws;
  short* qkv  = (short*)(ws + 0);            // 4096 x 3072 bf16 = 25165824 B
  short* vtb  = (short*)(ws + 25165824);     // 2*8*64*2048 bf16 = 4194304 B
  short* xb   = (short*)(ws + 29360128);     // 4096 x 2048 bf16 = 16777216 B (later reused as attn)
  short* attn = xb;                          // overlay: xb dead after QKV GEMM
  short* wT   = (short*)(ws + 46137344);     // 3072 x 2048 bf16 = 12582912 B (later reused for woT)
  float* ct   = (float*)(ws + 58720256);     // 2048*32 f32
  float* st   = (float*)(ws + 58982400);     // 2048*32 f32

  // 1. convert x
  cvt_kernel<<<8192, 256, 0, stream>>>(x, xb, 8388608);
  // 2. transpose+convert wq/wk/wv into fused [3072][2048]
  transcvt_kernel<<<dim3(32, 32), 256, 0, stream>>>(wq, wT, 2048, 2048);
  transcvt_kernel<<<dim3(8, 32), 256, 0, stream>>>(wk, wT + (size_t)2048 * 2048, 2048, 512);
  transcvt_kernel<<<dim3(8, 32), 256, 0, stream>>>(wv, wT + (size_t)2560 * 2048, 2048, 512);
  // 3. cos/sin table
  sincos_kernel<<<256, 256, 0, stream>>>(freqs, ct, st);
  // 4. fused QKV projection
  gemm_bt<0><<<dim3(32, 24), 256, 0, stream>>>(xb, wT, qkv, 4096, 3072, 2048);
  // 5. wo transpose (overlays wT — safe after QKV GEMM)
  transcvt_kernel<<<dim3(32, 32), 256, 0, stream>>>(wo, wT, 2048, 2048);
  // 6. RoPE on Q and K
  rope_kernel<<<20480, 256, 0, stream>>>(qkv, ct, st);
  // 7. V transpose
  transv_kernel<<<dim3(32, 16), 256, 0, stream>>>(qkv, vtb);
  // 8. attention
  attn_kernel<<<dim3(16, 32, 2), 256, 0, stream>>>(qkv, vtb, attn);
  // 9. output projection (fp32 store)
  gemm_bt<1><<<dim3(32, 16), 256, 0, stream>>>(attn, wT, d_out, 4096, 2048, 2048);
}

// Round 6
// 440.599 us; speedup vs baseline: 1.0755x; 1.0755x over previous
//
#include <hip/hip_runtime.h>

typedef __attribute__((ext_vector_type(8))) __bf16 bf16x8;
typedef __attribute__((ext_vector_type(4)))  float f32x4;
typedef __attribute__((ext_vector_type(16))) float f32x16;

__device__ __forceinline__ unsigned short f2bfu(float x) {
  union { float f; unsigned u; } v; v.f = x;
  unsigned r = v.u + 0x7fffu + ((v.u >> 16) & 1u);
  return (unsigned short)(r >> 16);
}
__device__ __forceinline__ float bf2f(unsigned short u) {
  union { unsigned u; float f; } v; v.u = ((unsigned)u) << 16;
  return v.f;
}
__device__ __forceinline__ unsigned pkbf(float a, float b) {
  return (unsigned)f2bfu(a) | ((unsigned)f2bfu(b) << 16);
}
__device__ __forceinline__ unsigned pk2(float a, float b) {
  union { __bf16 h[2]; unsigned u; } t;
  t.h[0] = (__bf16)a; t.h[1] = (__bf16)b;
  return t.u;
}
__device__ __forceinline__ void gload16(const void* g, void* l) {
  __builtin_amdgcn_global_load_lds((const __attribute__((address_space(1))) unsigned*)g,
                                   (__attribute__((address_space(3))) unsigned*)l, 16, 0, 0);
}
__device__ __forceinline__ bf16x8 mk8(unsigned a, unsigned b, unsigned c, unsigned d) {
  union { unsigned u[4]; bf16x8 v; } t;
  t.u[0] = a; t.u[1] = b; t.u[2] = c; t.u[3] = d; return t.v;
}

// ---------- fp32 -> bf16 convert ----------
__global__ void cvt_kernel(const float* __restrict__ s, short* __restrict__ d, int n) {
  int i = (blockIdx.x * 256 + threadIdx.x) * 4;
  if (i >= n) return;
  float4 v = *(const float4*)(s + i);
  short4 o;
  o.x = (short)f2bfu(v.x); o.y = (short)f2bfu(v.y);
  o.z = (short)f2bfu(v.z); o.w = (short)f2bfu(v.w);
  *(short4*)(d + i) = o;
}

// ---------- fp32 [R][C] -> bf16 [C][R] (weight transpose+convert) ----------
__global__ void transcvt_kernel(const float* __restrict__ src, short* __restrict__ dst,
                                int R, int C) {
  __shared__ __align__(16) float tl[64][65];
  int c0 = blockIdx.x * 64, r0 = blockIdx.y * 64;
  int t = threadIdx.x;
  int tr = t >> 4, tc = (t & 15) * 4;
#pragma unroll
  for (int i = 0; i < 4; i++) {
    int r = i * 16 + tr;
    float4 v = *(const float4*)(src + (size_t)(r0 + r) * C + c0 + tc);
    tl[r][tc] = v.x; tl[r][tc + 1] = v.y; tl[r][tc + 2] = v.z; tl[r][tc + 3] = v.w;
  }
  __syncthreads();
#pragma unroll
  for (int i = 0; i < 4; i++) {
    int cr = i * 16 + tr;
    short4 o;
    o.x = (short)f2bfu(tl[tc][cr]);
    o.y = (short)f2bfu(tl[tc + 1][cr]);
    o.z = (short)f2bfu(tl[tc + 2][cr]);
    o.w = (short)f2bfu(tl[tc + 3][cr]);
    *(short4*)(dst + (size_t)(c0 + cr) * R + r0 + tc) = o;
  }
}

// ---------- cos/sin table ----------
__global__ void sincos_kernel(const float* __restrict__ freqs, float* __restrict__ ct,
                              float* __restrict__ st) {
  int i = blockIdx.x * 256 + threadIdx.x; // 65536 = 2048*32
  float f = freqs[i];
  ct[i] = cosf(f);
  st[i] = sinf(f);
}

// ---------- bf16 GEMM: A[M][K] @ Bt[N][K]^T -> C[M][N]; m97 structure ----------
template <int OUTF32>
__global__ __launch_bounds__(256) void gemm_bt(const short* __restrict__ A,
                                               const short* __restrict__ Bt,
                                               void* __restrict__ C, int M, int N, int K) {
  __shared__ __align__(16) short Al[128 * 32];
  __shared__ __align__(16) short Bl[128 * 32];
  const int t = threadIdx.x, lane = t & 63, w = t >> 6;
  const int m0 = blockIdx.x * 128, n0 = blockIdx.y * 128;
  const int wm = (w & 1) * 64, wn = (w >> 1) * 64;
  f32x4 acc[4][4];
#pragma unroll
  for (int i = 0; i < 4; i++)
#pragma unroll
    for (int j = 0; j < 4; j++)
#pragma unroll
      for (int r = 0; r < 4; r++) acc[i][j][r] = 0.f;

  const int sr = t >> 2;  // staging row 0..63 (+64 on pass 1)
  const int ss = t & 3;   // 16B slot
  const int ldsbase = w * 512;  // elements

  for (int k0 = 0; k0 < K; k0 += 32) {
    __syncthreads();
#pragma unroll
    for (int p = 0; p < 2; p++) {
      int r = p * 64 + sr;
      int c = 8 * (ss ^ ((r >> 1) & 3));  // source-side swizzle, LDS stays linear
      gload16(A + (size_t)(m0 + r) * K + k0 + c, &Al[p * 2048 + ldsbase]);
      gload16(Bt + (size_t)(n0 + r) * K + k0 + c, &Bl[p * 2048 + ldsbase]);
    }
    __syncthreads();
    bf16x8 af[4], bg[4];
#pragma unroll
    for (int i = 0; i < 4; i++) {
      int ra = wm + i * 16 + (lane & 15);
      int sa = (lane >> 4) ^ ((ra >> 1) & 3);
      af[i] = *(const bf16x8*)(&Al[ra * 32 + sa * 8]);
      int rb = wn + i * 16 + (lane & 15);
      int sb = (lane >> 4) ^ ((rb >> 1) & 3);
      bg[i] = *(const bf16x8*)(&Bl[rb * 32 + sb * 8]);
    }
#pragma unroll
    for (int i = 0; i < 4; i++)
#pragma unroll
      for (int j = 0; j < 4; j++)
        acc[i][j] = __builtin_amdgcn_mfma_f32_16x16x32_bf16(af[i], bg[j], acc[i][j], 0, 0, 0);
  }
  const int cr = (lane >> 4) * 4, cc = lane & 15;
#pragma unroll
  for (int i = 0; i < 4; i++)
#pragma unroll
    for (int j = 0; j < 4; j++)
#pragma unroll
      for (int r = 0; r < 4; r++) {
        size_t idx = (size_t)(m0 + wm + i * 16 + cr + r) * N + (n0 + wn + j * 16 + cc);
        if (OUTF32) ((float*)C)[idx] = acc[i][j][r];
        else        ((short*)C)[idx] = (short)f2bfu(acc[i][j][r]);
      }
}

// ---------- RoPE in-place on qkv (Q cols 0..2047, K cols 2048..2559) ----------
__global__ void rope_kernel(short* __restrict__ qkv, const float* __restrict__ ct,
                            const float* __restrict__ st) {
  int idx = blockIdx.x * 256 + threadIdx.x;
  const int PQ = 4096 * 1024;
  int row, col, i;
  if (idx < PQ) {
    row = idx >> 10; int p = idx & 1023; int h = p >> 5; i = p & 31;
    col = h * 64 + 2 * i;
  } else {
    int k = idx - PQ; row = k >> 8; int p = k & 255; int kvh = p >> 5; i = p & 31;
    col = 2048 + kvh * 64 + 2 * i;
  }
  int s = row & 2047;
  unsigned* ptr = (unsigned*)(qkv + (size_t)row * 3072 + col);
  unsigned v = *ptr;
  float tr = bf2f((unsigned short)(v & 0xffff));
  float ti = bf2f((unsigned short)(v >> 16));
  float c = ct[(s << 5) + i], sn = st[(s << 5) + i];
  *ptr = pkbf(tr * c - ti * sn, tr * sn + ti * c);
}

// ---------- V transpose: qkv cols [2560..3071] -> vt[(b*8+kv)*64+d][s] ----------
__global__ void transv_kernel(const short* __restrict__ qkv, short* __restrict__ vt) {
  __shared__ __align__(16) short tl[64][72];
  int st0 = blockIdx.x * 64;
  int bkv = blockIdx.y; int b = bkv >> 3, kv = bkv & 7;
  int t = threadIdx.x;
  int rr = t >> 3, c8 = (t & 7) * 8;
#pragma unroll
  for (int i = 0; i < 2; i++) {
    int sl = i * 32 + rr;
    bf16x8 v = *(const bf16x8*)(qkv + (size_t)(b * 2048 + st0 + sl) * 3072 + 2560 + kv * 64 + c8);
    union { bf16x8 v; short s[8]; } u; u.v = v;
#pragma unroll
    for (int j = 0; j < 8; j++) tl[sl][c8 + j] = u.s[j];
  }
  __syncthreads();
#pragma unroll
  for (int i = 0; i < 2; i++) {
    int dl = i * 32 + rr;
    union { bf16x8 v; short s[8]; } o;
#pragma unroll
    for (int j = 0; j < 8; j++) o.s[j] = tl[c8 + j][dl];
    *(bf16x8*)(vt + ((size_t)(bkv * 64 + dl)) * 2048 + st0 + c8) = o.v;
  }
}

// ---------- causal GQA flash attention, KVBLK=64, 2-phase pipelined ----------
// grid (S/128, H, B); 4 waves x 32 q-rows; swapped QK^T; O^T accumulation
__global__ __launch_bounds__(256) void attn_kernel(const short* __restrict__ qkv,
                                                   const short* __restrict__ vt,
                                                   short* __restrict__ attn) {
  const int S = 2048, NC = 3072;
  __shared__ __align__(16) short sh[2][2][64 * 64];   // [buf][K/V] 32 KiB, dbuf

  const int qb = (int)(gridDim.x - 1 - blockIdx.x) * 128;   // longest blocks first
  const int h = blockIdx.y, b = blockIdx.z;
  const int kvh = h >> 2;
  const int t = threadIdx.x, lane = t & 63, w = t >> 6;
  const int q0 = qb + w * 32;
  const int qc = lane & 31, hi = lane >> 5;
  const int qg = q0 + qc;

  // Q fragments pre-scaled by 0.125*log2(e)
  bf16x8 bq[4];
  {
    const short* qp = qkv + (size_t)(b * S + qg) * NC + h * 64 + hi * 8;
    const float SC = 0.18033688011112042f;
#pragma unroll
    for (int kk = 0; kk < 4; kk++) {
      union { bf16x8 v; unsigned short s[8]; } u, o;
      u.v = *(const bf16x8*)(qp + kk * 16);
#pragma unroll
      for (int j = 0; j < 8; j++) o.s[j] = f2bfu(bf2f(u.s[j]) * SC);
      bq[kk] = o.v;
    }
  }

  f32x16 ot0, ot1;
#pragma unroll
  for (int r = 0; r < 16; r++) { ot0[r] = 0.f; ot1[r] = 0.f; }
  float m = -1e30f, l = 0.f;

  // staging geometry: wave w, pass p (0/1) stages rows p*32 + w*8 + (lane>>3)
  const int r8 = lane >> 3, sl8 = lane & 7;
  const int scol0 = 8 * (sl8 ^ ((r8 + w) & 7));        // swz(row)=(row+(row>>3))&7
  const int scol1 = 8 * (sl8 ^ ((r8 + 4 + w) & 7));
  const short* kptr = qkv + (size_t)(b * S + w * 8 + r8) * NC + 2048 + kvh * 64;
  const short* vptr = vt + (size_t)((b * 8 + kvh) * 64 + w * 8 + r8) * S;

  const int nt = (qb >> 6) + 2;

#define STAGE(tt, bb)                                                                   \
  do {                                                                                  \
    gload16(kptr + (size_t)((tt) * 64) * NC + scol0,        &sh[bb][0][(w * 8) * 64]);  \
    gload16(kptr + (size_t)((tt) * 64 + 32) * NC + scol1,   &sh[bb][0][(32 + w * 8) * 64]); \
    gload16(vptr + (size_t)(tt) * 64 + scol0,               &sh[bb][1][(w * 8) * 64]);  \
    gload16(vptr + (size_t)32 * S + (tt) * 64 + scol1,      &sh[bb][1][(32 + w * 8) * 64]); \
  } while (0)

  STAGE(0, 0);
  __syncthreads();

  for (int tt = 0; tt < nt; ++tt) {
    const int cur = tt & 1;
    if (tt + 1 < nt) STAGE(tt + 1, cur ^ 1);
    const int s0 = tt * 64;
    const short* kb = &sh[cur][0][0];
    const short* vb = &sh[cur][1][0];

    // swapped QK^T: S^T[k][q], two 32-row k-subtiles
    f32x16 cs0, cs1;
#pragma unroll
    for (int r = 0; r < 16; r++) { cs0[r] = 0.f; cs1[r] = 0.f; }
    const int kr0 = lane & 31, kr1 = kr0 + 32;
    const int sw0 = (kr0 + (kr0 >> 3)) & 7, sw1 = (kr1 + (kr1 >> 3)) & 7;
#pragma unroll
    for (int kk = 0; kk < 4; kk++) {
      bf16x8 a0 = *(const bf16x8*)(kb + kr0 * 64 + ((2 * kk + hi) ^ sw0) * 8);
      cs0 = __builtin_amdgcn_mfma_f32_32x32x16_bf16(a0, bq[kk], cs0, 0, 0, 0);
      bf16x8 a1 = *(const bf16x8*)(kb + kr1 * 64 + ((2 * kk + hi) ^ sw1) * 8);
      cs1 = __builtin_amdgcn_mfma_f32_32x32x16_bf16(a1, bq[kk], cs1, 0, 0, 0);
    }

    // causal mask (wave-uniform branch; scores pre-scaled via Q)
    if (s0 + 63 > q0) {
      const int qrel = qg - s0;
#pragma unroll
      for (int r = 0; r < 16; r++) {
        const int k0 = (r & 3) + 8 * (r >> 2) + 4 * hi;
        if (k0 > qrel)      cs0[r] = -1e30f;
        if (k0 + 32 > qrel) cs1[r] = -1e30f;
      }
    }

    // online softmax over 64 keys
    float mx = fmaxf(cs0[0], cs1[0]);
#pragma unroll
    for (int r = 1; r < 16; r++) mx = fmaxf(mx, fmaxf(cs0[r], cs1[r]));
    mx = fmaxf(mx, __shfl_xor(mx, 32, 64));
    const float mn = fmaxf(m, mx);
    const float rf = exp2f(m - mn);
    m = mn;
    float ls = 0.f;
#pragma unroll
    for (int r = 0; r < 16; r++) { cs0[r] = exp2f(cs0[r] - mn); ls += cs0[r]; }
#pragma unroll
    for (int r = 0; r < 16; r++) { cs1[r] = exp2f(cs1[r] - mn); ls += cs1[r]; }
    l = l * rf + ls;
#pragma unroll
    for (int r = 0; r < 16; r++) { ot0[r] *= rf; ot1[r] *= rf; }

    // P^T -> B fragments (pack + half-swap), per 32-key subtile
    unsigned x0[8], y0[8], x1[8], y1[8];
#pragma unroll
    for (int j = 0; j < 8; j++) x0[j] = pk2(cs0[2 * j], cs0[2 * j + 1]);
#pragma unroll
    for (int j = 0; j < 8; j++) y0[j] = (unsigned)__shfl_xor((int)x0[j], 32, 64);
#pragma unroll
    for (int j = 0; j < 8; j++) x1[j] = pk2(cs1[2 * j], cs1[2 * j + 1]);
#pragma unroll
    for (int j = 0; j < 8; j++) y1[j] = (unsigned)__shfl_xor((int)x1[j], 32, 64);
    bf16x8 pb0 = hi ? mk8(y0[2], y0[3], x0[2], x0[3]) : mk8(x0[0], x0[1], y0[0], y0[1]);
    bf16x8 pb1 = hi ? mk8(y0[6], y0[7], x0[6], x0[7]) : mk8(x0[4], x0[5], y0[4], y0[5]);
    bf16x8 pb2 = hi ? mk8(y1[2], y1[3], x1[2], x1[3]) : mk8(x1[0], x1[1], y1[0], y1[1]);
    bf16x8 pb3 = hi ? mk8(y1[6], y1[7], x1[6], x1[7]) : mk8(x1[4], x1[5], y1[4], y1[5]);

    // PV: O^T[d][q] += V^T[d][k] * P^T[k][q]
    const int dl = lane & 31;
    {
      const int d = dl;
      const int swd = (d + (d >> 3)) & 7;
      bf16x8 v0 = *(const bf16x8*)(vb + d * 64 + ((0 + hi) ^ swd) * 8);
      bf16x8 v1 = *(const bf16x8*)(vb + d * 64 + ((2 + hi) ^ swd) * 8);
      bf16x8 v2 = *(const bf16x8*)(vb + d * 64 + ((4 + hi) ^ swd) * 8);
      bf16x8 v3 = *(const bf16x8*)(vb + d * 64 + ((6 + hi) ^ swd) * 8);
      ot0 = __builtin_amdgcn_mfma_f32_32x32x16_bf16(v0, pb0, ot0, 0, 0, 0);
      ot0 = __builtin_amdgcn_mfma_f32_32x32x16_bf16(v1, pb1, ot0, 0, 0, 0);
      ot0 = __builtin_amdgcn_mfma_f32_32x32x16_bf16(v2, pb2, ot0, 0, 0, 0);
      ot0 = __builtin_amdgcn_mfma_f32_32x32x16_bf16(v3, pb3, ot0, 0, 0, 0);
    }
    {
      const int d = 32 + dl;
      const int swd = (d + (d >> 3)) & 7;
      bf16x8 v0 = *(const bf16x8*)(vb + d * 64 + ((0 + hi) ^ swd) * 8);
      bf16x8 v1 = *(const bf16x8*)(vb + d * 64 + ((2 + hi) ^ swd) * 8);
      bf16x8 v2 = *(const bf16x8*)(vb + d * 64 + ((4 + hi) ^ swd) * 8);
      bf16x8 v3 = *(const bf16x8*)(vb + d * 64 + ((6 + hi) ^ swd) * 8);
      ot1 = __builtin_amdgcn_mfma_f32_32x32x16_bf16(v0, pb0, ot1, 0, 0, 0);
      ot1 = __builtin_amdgcn_mfma_f32_32x32x16_bf16(v1, pb1, ot1, 0, 0, 0);
      ot1 = __builtin_amdgcn_mfma_f32_32x32x16_bf16(v2, pb2, ot1, 0, 0, 0);
      ot1 = __builtin_amdgcn_mfma_f32_32x32x16_bf16(v3, pb3, ot1, 0, 0, 0);
    }
    __syncthreads();  // stage(t+1) drained; all waves done reading buf[cur]
  }
#undef STAGE

  // epilogue: O^T -> O via LDS (overlay on sh; safe after loop-final barrier)
  short (*ol)[32 * 72] = (short (*)[32 * 72]) & sh[0][0][0];
  float lt = l + __shfl_xor(l, 32, 64);
  float inv = 1.0f / lt;
#pragma unroll
  for (int dh = 0; dh < 2; dh++) {
#pragma unroll
    for (int j = 0; j < 8; j++) {
      int d = ((2 * j) & 3) + 8 * ((2 * j) >> 2) + 4 * hi + 32 * dh;
      float a = (dh ? ot1[2 * j] : ot0[2 * j]) * inv;
      float bb = (dh ? ot1[2 * j + 1] : ot0[2 * j + 1]) * inv;
      *(unsigned*)(&ol[w][qc * 72 + d]) = pkbf(a, bb);
    }
  }
  __syncthreads();
  const int qr = lane >> 1, part = lane & 1;
  short* og = attn + (size_t)(b * S + q0 + qr) * 2048 + h * 64 + part * 32;
  const short* ip = &ol[w][qr * 72 + part * 32];
#pragma unroll
  for (int i2 = 0; i2 < 4; i2++) *(bf16x8*)(og + i2 * 8) = *(const bf16x8*)(ip + i2 * 8);
}

extern "C" void kernel_launch(void* const* d_in, const int* in_sizes, int n_in,
                              void* d_out, int out_size, void* d_ws, size_t ws_size,
                              hipStream_t stream) {
  (void)in_sizes; (void)n_in; (void)out_size; (void)ws_size;
  const float* x     = (const float*)d_in[0];
  const float* wq    = (const float*)d_in[1];
  const float* wk    = (const float*)d_in[2];
  const float* wv    = (const float*)d_in[3];
  const float* wo    = (const float*)d_in[4];
  const float* freqs = (const float*)d_in[5];

  char* ws = (char*)d_ws;
  short* qkv  = (short*)(ws + 0);            // 4096 x 3072 bf16 = 25165824 B
  short* vtb  = (short*)(ws + 25165824);     // 2*8*64*2048 bf16 = 4194304 B
  short* xb   = (short*)(ws + 29360128);     // 4096 x 2048 bf16 (later reused as attn)
  short* attn = xb;                          // overlay: xb dead after QKV GEMM
  short* wT   = (short*)(ws + 46137344);     // 3072 x 2048 bf16 (later reused for woT)
  float* ct   = (float*)(ws + 58720256);     // 2048*32 f32
  float* st   = (float*)(ws + 58982400);     // 2048*32 f32

  // 1. convert x
  cvt_kernel<<<8192, 256, 0, stream>>>(x, xb, 8388608);
  // 2. transpose+convert wq/wk/wv into fused [3072][2048]
  transcvt_kernel<<<dim3(32, 32), 256, 0, stream>>>(wq, wT, 2048, 2048);
  transcvt_kernel<<<dim3(8, 32), 256, 0, stream>>>(wk, wT + (size_t)2048 * 2048, 2048, 512);
  transcvt_kernel<<<dim3(8, 32), 256, 0, stream>>>(wv, wT + (size_t)2560 * 2048, 2048, 512);
  // 3. cos/sin table
  sincos_kernel<<<256, 256, 0, stream>>>(freqs, ct, st);
  // 4. fused QKV projection
  gemm_bt<0><<<dim3(32, 24), 256, 0, stream>>>(xb, wT, qkv, 4096, 3072, 2048);
  // 5. wo transpose (overlays wT — safe after QKV GEMM)
  transcvt_kernel<<<dim3(32, 32), 256, 0, stream>>>(wo, wT, 2048, 2048);
  // 6. RoPE on Q and K
  rope_kernel<<<20480, 256, 0, stream>>>(qkv, ct, st);
  // 7. V transpose
  transv_kernel<<<dim3(32, 16), 256, 0, stream>>>(qkv, vtb);
  // 8. attention
  attn_kernel<<<dim3(16, 32, 2), 256, 0, stream>>>(qkv, vtb, attn);
  // 9. output projection (fp32 store)
  gemm_bt<1><<<dim3(32, 16), 256, 0, stream>>>(attn, wT, d_out, 4096, 2048, 2048);
}

// Round 8
// 383.507 us; speedup vs baseline: 1.2356x; 1.1489x over previous
//
#include <hip/hip_runtime.h>

typedef __attribute__((ext_vector_type(8))) __bf16 bf16x8;
typedef __attribute__((ext_vector_type(4)))  float f32x4;
typedef __attribute__((ext_vector_type(16))) float f32x16;

__device__ __forceinline__ unsigned short f2bfu(float x) {
  union { float f; unsigned u; } v; v.f = x;
  unsigned r = v.u + 0x7fffu + ((v.u >> 16) & 1u);
  return (unsigned short)(r >> 16);
}
__device__ __forceinline__ float bf2f(unsigned short u) {
  union { unsigned u; float f; } v; v.u = ((unsigned)u) << 16;
  return v.f;
}
__device__ __forceinline__ unsigned pkbf(float a, float b) {
  return (unsigned)f2bfu(a) | ((unsigned)f2bfu(b) << 16);
}
__device__ __forceinline__ unsigned pk2(float a, float b) {
  union { __bf16 h[2]; unsigned u; } t;
  t.h[0] = (__bf16)a; t.h[1] = (__bf16)b;
  return t.u;
}
__device__ __forceinline__ void gload16(const void* g, void* l) {
  __builtin_amdgcn_global_load_lds((const __attribute__((address_space(1))) unsigned*)g,
                                   (__attribute__((address_space(3))) unsigned*)l, 16, 0, 0);
}
__device__ __forceinline__ bf16x8 mk8(unsigned a, unsigned b, unsigned c, unsigned d) {
  union { unsigned u[4]; bf16x8 v; } t;
  t.u[0] = a; t.u[1] = b; t.u[2] = c; t.u[3] = d; return t.v;
}

// ---------- fp32 -> bf16 convert ----------
__global__ void cvt_kernel(const float* __restrict__ s, short* __restrict__ d, int n) {
  int i = (blockIdx.x * 256 + threadIdx.x) * 4;
  if (i >= n) return;
  float4 v = *(const float4*)(s + i);
  short4 o;
  o.x = (short)f2bfu(v.x); o.y = (short)f2bfu(v.y);
  o.z = (short)f2bfu(v.z); o.w = (short)f2bfu(v.w);
  *(short4*)(d + i) = o;
}

// ---------- fp32 [R][C] -> bf16 [C][R] (weight transpose+convert) ----------
__global__ void transcvt_kernel(const float* __restrict__ src, short* __restrict__ dst,
                                int R, int C) {
  __shared__ __align__(16) float tl[64][65];
  int c0 = blockIdx.x * 64, r0 = blockIdx.y * 64;
  int t = threadIdx.x;
  int tr = t >> 4, tc = (t & 15) * 4;
#pragma unroll
  for (int i = 0; i < 4; i++) {
    int r = i * 16 + tr;
    float4 v = *(const float4*)(src + (size_t)(r0 + r) * C + c0 + tc);
    tl[r][tc] = v.x; tl[r][tc + 1] = v.y; tl[r][tc + 2] = v.z; tl[r][tc + 3] = v.w;
  }
  __syncthreads();
#pragma unroll
  for (int i = 0; i < 4; i++) {
    int cr = i * 16 + tr;
    short4 o;
    o.x = (short)f2bfu(tl[tc][cr]);
    o.y = (short)f2bfu(tl[tc + 1][cr]);
    o.z = (short)f2bfu(tl[tc + 2][cr]);
    o.w = (short)f2bfu(tl[tc + 3][cr]);
    *(short4*)(dst + (size_t)(c0 + cr) * R + r0 + tc) = o;
  }
}

// ---------- cos/sin table ----------
__global__ void sincos_kernel(const float* __restrict__ freqs, float* __restrict__ ct,
                              float* __restrict__ st) {
  int i = blockIdx.x * 256 + threadIdx.x; // 65536 = 2048*32
  float f = freqs[i];
  ct[i] = cosf(f);
  st[i] = sinf(f);
}

// ---------- bf16 GEMM: A[M][K] @ Bt[N][K]^T -> C[M][N]; m97 structure ----------
template <int OUTF32>
__global__ __launch_bounds__(256) void gemm_bt(const short* __restrict__ A,
                                               const short* __restrict__ Bt,
                                               void* __restrict__ C, int M, int N, int K) {
  __shared__ __align__(16) short Al[128 * 32];
  __shared__ __align__(16) short Bl[128 * 32];
  const int t = threadIdx.x, lane = t & 63, w = t >> 6;
  const int m0 = blockIdx.x * 128, n0 = blockIdx.y * 128;
  const int wm = (w & 1) * 64, wn = (w >> 1) * 64;
  f32x4 acc[4][4];
#pragma unroll
  for (int i = 0; i < 4; i++)
#pragma unroll
    for (int j = 0; j < 4; j++)
#pragma unroll
      for (int r = 0; r < 4; r++) acc[i][j][r] = 0.f;

  const int sr = t >> 2;  // staging row 0..63 (+64 on pass 1)
  const int ss = t & 3;   // 16B slot
  const int ldsbase = w * 512;  // elements

  for (int k0 = 0; k0 < K; k0 += 32) {
    __syncthreads();
#pragma unroll
    for (int p = 0; p < 2; p++) {
      int r = p * 64 + sr;
      int c = 8 * (ss ^ ((r >> 1) & 3));  // source-side swizzle, LDS stays linear
      gload16(A + (size_t)(m0 + r) * K + k0 + c, &Al[p * 2048 + ldsbase]);
      gload16(Bt + (size_t)(n0 + r) * K + k0 + c, &Bl[p * 2048 + ldsbase]);
    }
    __syncthreads();
    bf16x8 af[4], bg[4];
#pragma unroll
    for (int i = 0; i < 4; i++) {
      int ra = wm + i * 16 + (lane & 15);
      int sa = (lane >> 4) ^ ((ra >> 1) & 3);
      af[i] = *(const bf16x8*)(&Al[ra * 32 + sa * 8]);
      int rb = wn + i * 16 + (lane & 15);
      int sb = (lane >> 4) ^ ((rb >> 1) & 3);
      bg[i] = *(const bf16x8*)(&Bl[rb * 32 + sb * 8]);
    }
#pragma unroll
    for (int i = 0; i < 4; i++)
#pragma unroll
      for (int j = 0; j < 4; j++)
        acc[i][j] = __builtin_amdgcn_mfma_f32_16x16x32_bf16(af[i], bg[j], acc[i][j], 0, 0, 0);
  }
  const int cr = (lane >> 4) * 4, cc = lane & 15;
#pragma unroll
  for (int i = 0; i < 4; i++)
#pragma unroll
    for (int j = 0; j < 4; j++)
#pragma unroll
      for (int r = 0; r < 4; r++) {
        size_t idx = (size_t)(m0 + wm + i * 16 + cr + r) * N + (n0 + wn + j * 16 + cc);
        if (OUTF32) ((float*)C)[idx] = acc[i][j][r];
        else        ((short*)C)[idx] = (short)f2bfu(acc[i][j][r]);
      }
}

// ---------- RoPE in-place on qkv (Q cols 0..2047, K cols 2048..2559) ----------
__global__ void rope_kernel(short* __restrict__ qkv, const float* __restrict__ ct,
                            const float* __restrict__ st) {
  int idx = blockIdx.x * 256 + threadIdx.x;
  const int PQ = 4096 * 1024;
  int row, col, i;
  if (idx < PQ) {
    row = idx >> 10; int p = idx & 1023; int h = p >> 5; i = p & 31;
    col = h * 64 + 2 * i;
  } else {
    int k = idx - PQ; row = k >> 8; int p = k & 255; int kvh = p >> 5; i = p & 31;
    col = 2048 + kvh * 64 + 2 * i;
  }
  int s = row & 2047;
  unsigned* ptr = (unsigned*)(qkv + (size_t)row * 3072 + col);
  unsigned v = *ptr;
  float tr = bf2f((unsigned short)(v & 0xffff));
  float ti = bf2f((unsigned short)(v >> 16));
  float c = ct[(s << 5) + i], sn = st[(s << 5) + i];
  *ptr = pkbf(tr * c - ti * sn, tr * sn + ti * c);
}

// ---------- V transpose: qkv cols [2560..3071] -> vt[(b*8+kv)*64+d][s] ----------
__global__ void transv_kernel(const short* __restrict__ qkv, short* __restrict__ vt) {
  __shared__ __align__(16) short tl[64][72];
  int st0 = blockIdx.x * 64;
  int bkv = blockIdx.y; int b = bkv >> 3, kv = bkv & 7;
  int t = threadIdx.x;
  int rr = t >> 3, c8 = (t & 7) * 8;
#pragma unroll
  for (int i = 0; i < 2; i++) {
    int sl = i * 32 + rr;
    bf16x8 v = *(const bf16x8*)(qkv + (size_t)(b * 2048 + st0 + sl) * 3072 + 2560 + kv * 64 + c8);
    union { bf16x8 v; short s[8]; } u; u.v = v;
#pragma unroll
    for (int j = 0; j < 8; j++) tl[sl][c8 + j] = u.s[j];
  }
  __syncthreads();
#pragma unroll
  for (int i = 0; i < 2; i++) {
    int dl = i * 32 + rr;
    union { bf16x8 v; short s[8]; } o;
#pragma unroll
    for (int j = 0; j < 8; j++) o.s[j] = tl[c8 + j][dl];
    *(bf16x8*)(vt + ((size_t)(bkv * 64 + dl)) * 2048 + st0 + c8) = o.v;
  }
}

// ---------- causal GQA flash attention, KVBLK=64, 2-phase pipelined ----------
// grid (H, S/128, B): x=head so co-resident blocks share K/V; y-> qb via
// balanced pairing perm (y,y+8 sum to 15) so every CU gets equal total work
__global__ __launch_bounds__(256) void attn_kernel(const short* __restrict__ qkv,
                                                   const short* __restrict__ vt,
                                                   short* __restrict__ attn) {
  const int S = 2048, NC = 3072;
  __shared__ __align__(16) short sh[2][2][64 * 64];   // [buf][K/V] 32 KiB, dbuf

  const int y = blockIdx.y;
  const int qi = (y < 8) ? y : (23 - y);   // perm[y]+perm[y+8] == 15
  const int qb = qi * 128;
  const int h = blockIdx.x, b = blockIdx.z;
  const int kvh = h >> 2;
  const int t = threadIdx.x, lane = t & 63, w = t >> 6;
  const int q0 = qb + w * 32;
  const int qc = lane & 31, hi = lane >> 5;
  const int qg = q0 + qc;

  // Q fragments pre-scaled by 0.125*log2(e)
  bf16x8 bq[4];
  {
    const short* qp = qkv + (size_t)(b * S + qg) * NC + h * 64 + hi * 8;
    const float SC = 0.18033688011112042f;
#pragma unroll
    for (int kk = 0; kk < 4; kk++) {
      union { bf16x8 v; unsigned short s[8]; } u, o;
      u.v = *(const bf16x8*)(qp + kk * 16);
#pragma unroll
      for (int j = 0; j < 8; j++) o.s[j] = f2bfu(bf2f(u.s[j]) * SC);
      bq[kk] = o.v;
    }
  }

  f32x16 ot0, ot1;
#pragma unroll
  for (int r = 0; r < 16; r++) { ot0[r] = 0.f; ot1[r] = 0.f; }
  float m = -1e30f, l = 0.f;

  // staging geometry: wave w, pass p (0/1) stages rows p*32 + w*8 + (lane>>3)
  const int r8 = lane >> 3, sl8 = lane & 7;
  const int scol0 = 8 * (sl8 ^ ((r8 + w) & 7));        // swz(row)=(row+(row>>3))&7
  const int scol1 = 8 * (sl8 ^ ((r8 + 4 + w) & 7));
  const short* kptr = qkv + (size_t)(b * S + w * 8 + r8) * NC + 2048 + kvh * 64;
  const short* vptr = vt + (size_t)((b * 8 + kvh) * 64 + w * 8 + r8) * S;

  const int nt = (qb >> 6) + 2;

#define STAGE(tt, bb)                                                                   \
  do {                                                                                  \
    gload16(kptr + (size_t)((tt) * 64) * NC + scol0,        &sh[bb][0][(w * 8) * 64]);  \
    gload16(kptr + (size_t)((tt) * 64 + 32) * NC + scol1,   &sh[bb][0][(32 + w * 8) * 64]); \
    gload16(vptr + (size_t)(tt) * 64 + scol0,               &sh[bb][1][(w * 8) * 64]);  \
    gload16(vptr + (size_t)32 * S + (tt) * 64 + scol1,      &sh[bb][1][(32 + w * 8) * 64]); \
  } while (0)

  STAGE(0, 0);
  __syncthreads();

  for (int tt = 0; tt < nt; ++tt) {
    const int cur = tt & 1;
    if (tt + 1 < nt) STAGE(tt + 1, cur ^ 1);
    const int s0 = tt * 64;
    const short* kb = &sh[cur][0][0];
    const short* vb = &sh[cur][1][0];

    // swapped QK^T: S^T[k][q], two 32-row k-subtiles
    f32x16 cs0, cs1;
#pragma unroll
    for (int r = 0; r < 16; r++) { cs0[r] = 0.f; cs1[r] = 0.f; }
    const int kr0 = lane & 31, kr1 = kr0 + 32;
    const int sw0 = (kr0 + (kr0 >> 3)) & 7, sw1 = (kr1 + (kr1 >> 3)) & 7;
#pragma unroll
    for (int kk = 0; kk < 4; kk++) {
      bf16x8 a0 = *(const bf16x8*)(kb + kr0 * 64 + ((2 * kk + hi) ^ sw0) * 8);
      cs0 = __builtin_amdgcn_mfma_f32_32x32x16_bf16(a0, bq[kk], cs0, 0, 0, 0);
      bf16x8 a1 = *(const bf16x8*)(kb + kr1 * 64 + ((2 * kk + hi) ^ sw1) * 8);
      cs1 = __builtin_amdgcn_mfma_f32_32x32x16_bf16(a1, bq[kk], cs1, 0, 0, 0);
    }

    // causal mask (wave-uniform branch; scores pre-scaled via Q)
    if (s0 + 63 > q0) {
      const int qrel = qg - s0;
#pragma unroll
      for (int r = 0; r < 16; r++) {
        const int k0 = (r & 3) + 8 * (r >> 2) + 4 * hi;
        if (k0 > qrel)      cs0[r] = -1e30f;
        if (k0 + 32 > qrel) cs1[r] = -1e30f;
      }
    }

    // online softmax over 64 keys, defer-max (T13, THR=8)
    float mx = fmaxf(cs0[0], cs1[0]);
#pragma unroll
    for (int r = 1; r < 16; r++) mx = fmaxf(mx, fmaxf(cs0[r], cs1[r]));
    mx = fmaxf(mx, __shfl_xor(mx, 32, 64));
    if (!__all(mx - m <= 8.f)) {
      const float mn = fmaxf(m, mx);
      const float rf = exp2f(m - mn);
      m = mn;
      l *= rf;
#pragma unroll
      for (int r = 0; r < 16; r++) { ot0[r] *= rf; ot1[r] *= rf; }
    }
    float ls = 0.f;
#pragma unroll
    for (int r = 0; r < 16; r++) { cs0[r] = exp2f(cs0[r] - m); ls += cs0[r]; }
#pragma unroll
    for (int r = 0; r < 16; r++) { cs1[r] = exp2f(cs1[r] - m); ls += cs1[r]; }
    l += ls;

    // P^T -> B fragments (pack + half-swap), per 32-key subtile
    unsigned x0[8], y0[8], x1[8], y1[8];
#pragma unroll
    for (int j = 0; j < 8; j++) x0[j] = pk2(cs0[2 * j], cs0[2 * j + 1]);
#pragma unroll
    for (int j = 0; j < 8; j++) y0[j] = (unsigned)__shfl_xor((int)x0[j], 32, 64);
#pragma unroll
    for (int j = 0; j < 8; j++) x1[j] = pk2(cs1[2 * j], cs1[2 * j + 1]);
#pragma unroll
    for (int j = 0; j < 8; j++) y1[j] = (unsigned)__shfl_xor((int)x1[j], 32, 64);
    bf16x8 pb0 = hi ? mk8(y0[2], y0[3], x0[2], x0[3]) : mk8(x0[0], x0[1], y0[0], y0[1]);
    bf16x8 pb1 = hi ? mk8(y0[6], y0[7], x0[6], x0[7]) : mk8(x0[4], x0[5], y0[4], y0[5]);
    bf16x8 pb2 = hi ? mk8(y1[2], y1[3], x1[2], x1[3]) : mk8(x1[0], x1[1], y1[0], y1[1]);
    bf16x8 pb3 = hi ? mk8(y1[6], y1[7], x1[6], x1[7]) : mk8(x1[4], x1[5], y1[4], y1[5]);

    // PV: O^T[d][q] += V^T[d][k] * P^T[k][q]
    const int dl = lane & 31;
    {
      const int d = dl;
      const int swd = (d + (d >> 3)) & 7;
      bf16x8 v0 = *(const bf16x8*)(vb + d * 64 + ((0 + hi) ^ swd) * 8);
      bf16x8 v1 = *(const bf16x8*)(vb + d * 64 + ((2 + hi) ^ swd) * 8);
      bf16x8 v2 = *(const bf16x8*)(vb + d * 64 + ((4 + hi) ^ swd) * 8);
      bf16x8 v3 = *(const bf16x8*)(vb + d * 64 + ((6 + hi) ^ swd) * 8);
      ot0 = __builtin_amdgcn_mfma_f32_32x32x16_bf16(v0, pb0, ot0, 0, 0, 0);
      ot0 = __builtin_amdgcn_mfma_f32_32x32x16_bf16(v1, pb1, ot0, 0, 0, 0);
      ot0 = __builtin_amdgcn_mfma_f32_32x32x16_bf16(v2, pb2, ot0, 0, 0, 0);
      ot0 = __builtin_amdgcn_mfma_f32_32x32x16_bf16(v3, pb3, ot0, 0, 0, 0);
    }
    {
      const int d = 32 + dl;
      const int swd = (d + (d >> 3)) & 7;
      bf16x8 v0 = *(const bf16x8*)(vb + d * 64 + ((0 + hi) ^ swd) * 8);
      bf16x8 v1 = *(const bf16x8*)(vb + d * 64 + ((2 + hi) ^ swd) * 8);
      bf16x8 v2 = *(const bf16x8*)(vb + d * 64 + ((4 + hi) ^ swd) * 8);
      bf16x8 v3 = *(const bf16x8*)(vb + d * 64 + ((6 + hi) ^ swd) * 8);
      ot1 = __builtin_amdgcn_mfma_f32_32x32x16_bf16(v0, pb0, ot1, 0, 0, 0);
      ot1 = __builtin_amdgcn_mfma_f32_32x32x16_bf16(v1, pb1, ot1, 0, 0, 0);
      ot1 = __builtin_amdgcn_mfma_f32_32x32x16_bf16(v2, pb2, ot1, 0, 0, 0);
      ot1 = __builtin_amdgcn_mfma_f32_32x32x16_bf16(v3, pb3, ot1, 0, 0, 0);
    }
    __syncthreads();  // stage(t+1) drained; all waves done reading buf[cur]
  }
#undef STAGE

  // epilogue: O^T -> O via LDS (overlay on sh; safe after loop-final barrier)
  short (*ol)[32 * 72] = (short (*)[32 * 72]) & sh[0][0][0];
  float lt = l + __shfl_xor(l, 32, 64);
  float inv = 1.0f / lt;
#pragma unroll
  for (int dh = 0; dh < 2; dh++) {
#pragma unroll
    for (int j = 0; j < 8; j++) {
      int d = ((2 * j) & 3) + 8 * ((2 * j) >> 2) + 4 * hi + 32 * dh;
      float a = (dh ? ot1[2 * j] : ot0[2 * j]) * inv;
      float bb = (dh ? ot1[2 * j + 1] : ot0[2 * j + 1]) * inv;
      *(unsigned*)(&ol[w][qc * 72 + d]) = pkbf(a, bb);
    }
  }
  __syncthreads();
  const int qr = lane >> 1, part = lane & 1;
  short* og = attn + (size_t)(b * S + q0 + qr) * 2048 + h * 64 + part * 32;
  const short* ip = &ol[w][qr * 72 + part * 32];
#pragma unroll
  for (int i2 = 0; i2 < 4; i2++) *(bf16x8*)(og + i2 * 8) = *(const bf16x8*)(ip + i2 * 8);
}

extern "C" void kernel_launch(void* const* d_in, const int* in_sizes, int n_in,
                              void* d_out, int out_size, void* d_ws, size_t ws_size,
                              hipStream_t stream) {
  (void)in_sizes; (void)n_in; (void)out_size; (void)ws_size;
  const float* x     = (const float*)d_in[0];
  const float* wq    = (const float*)d_in[1];
  const float* wk    = (const float*)d_in[2];
  const float* wv    = (const float*)d_in[3];
  const float* wo    = (const float*)d_in[4];
  const float* freqs = (const float*)d_in[5];

  char* ws = (char*)d_ws;
  short* qkv  = (short*)(ws + 0);            // 4096 x 3072 bf16 = 25165824 B
  short* vtb  = (short*)(ws + 25165824);     // 2*8*64*2048 bf16 = 4194304 B
  short* xb   = (short*)(ws + 29360128);     // 4096 x 2048 bf16 (later reused as attn)
  short* attn = xb;                          // overlay: xb dead after QKV GEMM
  short* wT   = (short*)(ws + 46137344);     // 3072 x 2048 bf16 (later reused for woT)
  float* ct   = (float*)(ws + 58720256);     // 2048*32 f32
  float* st   = (float*)(ws + 58982400);     // 2048*32 f32

  // 1. convert x
  cvt_kernel<<<8192, 256, 0, stream>>>(x, xb, 8388608);
  // 2. transpose+convert wq/wk/wv into fused [3072][2048]
  transcvt_kernel<<<dim3(32, 32), 256, 0, stream>>>(wq, wT, 2048, 2048);
  transcvt_kernel<<<dim3(8, 32), 256, 0, stream>>>(wk, wT + (size_t)2048 * 2048, 2048, 512);
  transcvt_kernel<<<dim3(8, 32), 256, 0, stream>>>(wv, wT + (size_t)2560 * 2048, 2048, 512);
  // 3. cos/sin table
  sincos_kernel<<<256, 256, 0, stream>>>(freqs, ct, st);
  // 4. fused QKV projection
  gemm_bt<0><<<dim3(32, 24), 256, 0, stream>>>(xb, wT, qkv, 4096, 3072, 2048);
  // 5. wo transpose (overlays wT — safe after QKV GEMM)
  transcvt_kernel<<<dim3(32, 32), 256, 0, stream>>>(wo, wT, 2048, 2048);
  // 6. RoPE on Q and K
  rope_kernel<<<20480, 256, 0, stream>>>(qkv, ct, st);
  // 7. V transpose
  transv_kernel<<<dim3(32, 16), 256, 0, stream>>>(qkv, vtb);
  // 8. attention (x=head, y=qb via balanced perm, z=batch)
  attn_kernel<<<dim3(32, 16, 2), 256, 0, stream>>>(qkv, vtb, attn);
  // 9. output projection (fp32 store)
  gemm_bt<1><<<dim3(32, 16), 256, 0, stream>>>(attn, wT, d_out, 4096, 2048, 2048);
}